// Round 3
// baseline (410.880 us; speedup 1.0000x reference)
//
#include <hip/hip_runtime.h>

typedef unsigned short u16;
typedef __attribute__((ext_vector_type(8))) short short8;
typedef __attribute__((ext_vector_type(4))) float float4v;

#define TVB 7500
#define CTVB 480000

union U8S { short8 s; uint4 u; };

static __device__ __forceinline__ u16 f2bfc(float f) {   // round-half-up, 2 ops
    union { float f; unsigned u; } x; x.f = f;
    return (u16)((x.u + 0x8000u) >> 16);
}
// pack bf16(a) | bf16(b)<<16 : 2 adds + 1 v_perm
static __device__ __forceinline__ unsigned pk2(float a, float b) {
    union { float f; unsigned u; } xa, xb; xa.f = a; xb.f = b;
    return __builtin_amdgcn_perm(xb.u + 0x8000u, xa.u + 0x8000u, 0x07060302u);
}

// ---------------- Kernel A: attention score partials S_i[n,u,v] ----------------
// grid (25, 64), block 256. 12 t's per block (3 groups of 4).
__global__ __launch_bounds__(256, 3) void kA(
    const float* __restrict__ xg, const float* __restrict__ Wa, const float* __restrict__ ba,
    const float* __restrict__ Wb, const float* __restrict__ bb, float* __restrict__ Sws)
{
    __shared__ u16 xT[4][32][72];   // xT[tt][u][c]
    __shared__ u16 asT[3][32][72];  // a^T : [i][u][k=tt*16+ci]
    __shared__ u16 bsT[3][32][72];  // b^T : [i][v][k]
    const int tid  = threadIdx.x;
    const int lane = tid & 63;
    const int w    = tid >> 6;
    const int l15  = lane & 15;
    const int q    = lane >> 4;
    const int n    = blockIdx.y;
    const int t0   = blockIdx.x * 12;

    // zero xT pad rows u=25..31 (once; staging never touches them)
    for (int e = tid; e < 4 * 7 * 72; e += 256) {
        int tt = e / 504;
        int r  = e - tt * 504;
        xT[tt][25 + r / 72][r % 72] = 0;
    }

    // Wa/Wb A-frags (wave w<3 = subset i). A[m=ci][k=c]. 2 float4 loads + 4 perms per frag.
    short8 waf[2], wbf[2];
    float ba_r[4], bb_r[4];
    if (w < 3) {
        #pragma unroll
        for (int kf = 0; kf < 2; ++kf) {
            const float* pa = Wa + w * 1024 + l15 * 64 + kf * 32 + q * 8;
            const float* pb = Wb + w * 1024 + l15 * 64 + kf * 32 + q * 8;
            float4 a0 = *(const float4*)pa, a1 = *(const float4*)(pa + 4);
            float4 b0 = *(const float4*)pb, b1 = *(const float4*)(pb + 4);
            U8S ta, tb;
            ta.u = make_uint4(pk2(a0.x, a0.y), pk2(a0.z, a0.w), pk2(a1.x, a1.y), pk2(a1.z, a1.w));
            tb.u = make_uint4(pk2(b0.x, b0.y), pk2(b0.z, b0.w), pk2(b1.x, b1.y), pk2(b1.z, b1.w));
            waf[kf] = ta.s; wbf[kf] = tb.s;
        }
        #pragma unroll
        for (int r = 0; r < 4; ++r) {
            ba_r[r] = ba[w * 16 + q * 4 + r];
            bb_r[r] = bb[w * 16 + q * 4 + r];
        }
    }

    float4v accS[3];
    #pragma unroll
    for (int i = 0; i < 3; ++i) accS[i] = (float4v){0.f, 0.f, 0.f, 0.f};

    const float* xb = xg + (size_t)n * CTVB;

    for (int g = 0; g < 3; ++g) {
        __syncthreads();
        // stage 4 t's transposed, paired float2 loads (t0+g*4 is even -> 8B aligned)
        const float* xs = xb + (t0 + g * 4) * 25;
        #pragma unroll 2
        for (int e = tid; e < 3200; e += 256) {
            int c = e / 50;
            int p = e - c * 50;
            int j = 2 * p;
            float2 v2 = *(const float2*)(xs + c * TVB + j);
            int tt0 = j / 25, u0 = j - tt0 * 25;
            int j1 = j + 1;
            int tt1 = j1 / 25, u1 = j1 - tt1 * 25;
            xT[tt0][u0][c] = f2bfc(v2.x);
            xT[tt1][u1][c] = f2bfc(v2.y);
        }
        __syncthreads();
        if (w < 3) {
            #pragma unroll
            for (int tt = 0; tt < 4; ++tt) {
                float4v aA0 = {0,0,0,0}, aA1 = {0,0,0,0}, aB0 = {0,0,0,0}, aB1 = {0,0,0,0};
                #pragma unroll
                for (int kf = 0; kf < 2; ++kf) {
                    short8 x0 = *(const short8*)&xT[tt][l15][kf * 32 + q * 8];
                    short8 x1 = *(const short8*)&xT[tt][16 + l15][kf * 32 + q * 8];
                    aA0 = __builtin_amdgcn_mfma_f32_16x16x32_bf16(waf[kf], x0, aA0, 0, 0, 0);
                    aA1 = __builtin_amdgcn_mfma_f32_16x16x32_bf16(waf[kf], x1, aA1, 0, 0, 0);
                    aB0 = __builtin_amdgcn_mfma_f32_16x16x32_bf16(wbf[kf], x0, aB0, 0, 0, 0);
                    aB1 = __builtin_amdgcn_mfma_f32_16x16x32_bf16(wbf[kf], x1, aB1, 0, 0, 0);
                }
                int kb = tt * 16 + q * 4;
                uint2 ua0 = { pk2(aA0[0] + ba_r[0], aA0[1] + ba_r[1]), pk2(aA0[2] + ba_r[2], aA0[3] + ba_r[3]) };
                uint2 ua1 = { pk2(aA1[0] + ba_r[0], aA1[1] + ba_r[1]), pk2(aA1[2] + ba_r[2], aA1[3] + ba_r[3]) };
                uint2 ub0 = { pk2(aB0[0] + bb_r[0], aB0[1] + bb_r[1]), pk2(aB0[2] + bb_r[2], aB0[3] + bb_r[3]) };
                uint2 ub1 = { pk2(aB1[0] + bb_r[0], aB1[1] + bb_r[1]), pk2(aB1[2] + bb_r[2], aB1[3] + bb_r[3]) };
                *(uint2*)&asT[w][l15][kb]      = ua0;
                *(uint2*)&asT[w][16 + l15][kb] = ua1;
                *(uint2*)&bsT[w][l15][kb]      = ub0;
                *(uint2*)&bsT[w][16 + l15][kb] = ub1;
            }
        }
        __syncthreads();
        const int mt = w >> 1, nt = w & 1;
        #pragma unroll
        for (int i = 0; i < 3; ++i) {
            #pragma unroll
            for (int ks = 0; ks < 2; ++ks) {
                short8 af  = *(const short8*)&asT[i][mt * 16 + l15][ks * 32 + q * 8];
                short8 bf_ = *(const short8*)&bsT[i][nt * 16 + l15][ks * 32 + q * 8];
                accS[i] = __builtin_amdgcn_mfma_f32_16x16x32_bf16(af, bf_, accS[i], 0, 0, 0);
            }
        }
    }
    const int mt = w >> 1, nt = w & 1;
    #pragma unroll
    for (int i = 0; i < 3; ++i) {
        #pragma unroll
        for (int r = 0; r < 4; ++r) {
            int u = mt * 16 + q * 4 + r;
            int v = nt * 16 + l15;
            if (u < 25 && v < 25)
                atomicAdd(&Sws[(i * 64 + n) * 625 + u * 25 + v], accS[i][r]);
        }
    }
}

// ---------------- Kernel S: softmax over u (dim -2), + A_static + graph_attn ----------------
__global__ __launch_bounds__(64) void kS(float* __restrict__ Sws,
    const float* __restrict__ Ast, const float* __restrict__ Gat)
{
    int g = blockIdx.x;       // g = i*64 + n
    int i = g >> 6;
    int v = threadIdx.x;
    if (v >= 25) return;
    float vals[25];
    float m = -1e30f;
    #pragma unroll
    for (int u = 0; u < 25; ++u) {
        float s = Sws[g * 625 + u * 25 + v] * (1.0f / 4800.0f);
        vals[u] = s;
        m = fmaxf(m, s);
    }
    float sum = 0.f;
    #pragma unroll
    for (int u = 0; u < 25; ++u) { float e = __expf(vals[u] - m); vals[u] = e; sum += e; }
    float isum = 1.f / sum;
    #pragma unroll
    for (int u = 0; u < 25; ++u) {
        int idx = i * 625 + u * 25 + v;
        Sws[g * 625 + u * 25 + v] = vals[u] * isum + Ast[idx] + Gat[idx];
    }
}

// ---------------- Kernel B: out = relu(BN(sum_i Wg_i @ (X_t @ P_i)) + x) ----------------
// grid (100, 64), block 256. 3 t's per block. LDS 32.7KB -> 4 blocks/CU.
__global__ __launch_bounds__(256, 4) void kB(
    const float* __restrict__ xg, const float* __restrict__ Wgp, const float* __restrict__ bgp,
    const float* __restrict__ gam, const float* __restrict__ bet, const float* __restrict__ rmu,
    const float* __restrict__ rva, const float* __restrict__ attnw, float* __restrict__ outg)
{
    __shared__ u16 xsu[3][64][32];   // x[c][u], u padded to 32 with zeros
    __shared__ u16 ysT[32][200];     // Ycat^T : [v][k=i*64+c]
    __shared__ u16 pTs[3][32][40];   // attn^T : [i][v][u], zero-padded
    const int tid  = threadIdx.x;
    const int lane = tid & 63;
    const int w    = tid >> 6;
    const int l15  = lane & 15;
    const int q    = lane >> 4;
    const int n    = blockIdx.y;
    const int t0   = blockIdx.x * 3;

    for (int e = tid; e < 3 * 32 * 40; e += 256) ((u16*)pTs)[e] = 0;
    const float* xb = xg + (size_t)n * CTVB;
    // x staging: per c, run of 75 floats (3 t): 37 float2 pairs + 1 tail
    #pragma unroll 2
    for (int e = tid; e < 64 * 38; e += 256) {
        int c = e / 38;
        int p = e - c * 38;
        const float* src = xb + c * TVB + t0 * 25;
        if (p < 37) {
            int j = 2 * p;
            float2 v2 = *(const float2*)(src + j);
            int tt0 = j / 25, u0 = j - tt0 * 25;
            int j1 = j + 1;
            int tt1 = j1 / 25, u1 = j1 - tt1 * 25;
            xsu[tt0][c][u0] = f2bfc(v2.x);
            xsu[tt1][c][u1] = f2bfc(v2.y);
        } else {
            xsu[2][c][24] = f2bfc(src[74]);
        }
    }
    // zero pads u=25..31
    for (int e = tid; e < 3 * 64 * 7; e += 256) {
        int tt = e / 448;
        int r  = e - tt * 448;
        xsu[tt][r / 7][25 + r % 7] = 0;
    }
    for (int e = tid; e < 1875; e += 256) {
        int i = e / 625;
        int r = e - i * 625;
        int u = r / 25;
        int v = r - u * 25;
        pTs[i][v][u] = f2bfc(attnw[(i * 64 + n) * 625 + r]);
    }

    // Wg A-frags: 2 float4 loads + 4 perms per frag, held in registers.
    short8 wgf[6];
    #pragma unroll
    for (int kf = 0; kf < 6; ++kf) {
        int i  = kf >> 1;
        int c0 = (kf & 1) * 32 + q * 8;
        const float* p = Wgp + i * 4096 + (w * 16 + l15) * 64 + c0;
        float4 f0 = *(const float4*)p, f1 = *(const float4*)(p + 4);
        U8S t;
        t.u = make_uint4(pk2(f0.x, f0.y), pk2(f0.z, f0.w), pk2(f1.x, f1.y), pk2(f1.z, f1.w));
        wgf[kf] = t.s;
    }
    // BN constants per lane (o = w*16 + q*4 + r)
    float invr[4], add0r[4];
    #pragma unroll
    for (int r = 0; r < 4; ++r) {
        int o = w * 16 + q * 4 + r;
        float gv = gam[o], bt = bet[o], mu = rmu[o], vv = rva[o];
        float bgs = bgp[o] + bgp[64 + o] + bgp[128 + o];
        float iv = gv * rsqrtf(vv + 1e-5f);
        invr[r] = iv;
        add0r[r] = (bgs - mu) * iv + bt;
    }
    __syncthreads();
    // P B-frags in registers: B[k=u][n=v]
    short8 pf[3][2];
    #pragma unroll
    for (int i = 0; i < 3; ++i)
        #pragma unroll
        for (int nt = 0; nt < 2; ++nt)
            pf[i][nt] = *(const short8*)&pTs[i][nt * 16 + l15][q * 8];

    #pragma unroll
    for (int tl = 0; tl < 3; ++tl) {
        // Phase A: Y_i = X_t @ P_i
        short8 xf = *(const short8*)&xsu[tl][w * 16 + l15][q * 8];
        #pragma unroll
        for (int i = 0; i < 3; ++i) {
            #pragma unroll
            for (int nt = 0; nt < 2; ++nt) {
                float4v acc = {0, 0, 0, 0};
                acc = __builtin_amdgcn_mfma_f32_16x16x32_bf16(xf, pf[i][nt], acc, 0, 0, 0);
                uint2 pk = { pk2(acc[0], acc[1]), pk2(acc[2], acc[3]) };
                *(uint2*)&ysT[nt * 16 + l15][i * 64 + w * 16 + q * 4] = pk;
            }
        }
        __syncthreads();
        // Phase B: Out_t = WgCat(64x192) @ Ycat(192x25pad32); epilogue fused
        #pragma unroll
        for (int nt = 0; nt < 2; ++nt) {
            float4v acc = {0, 0, 0, 0};
            #pragma unroll
            for (int kf = 0; kf < 6; ++kf) {
                short8 yf = *(const short8*)&ysT[nt * 16 + l15][kf * 32 + q * 8];
                acc = __builtin_amdgcn_mfma_f32_16x16x32_bf16(wgf[kf], yf, acc, 0, 0, 0);
            }
            int v = nt * 16 + l15;
            if (v < 25) {
                int base_o = w * 16 + q * 4;
                const float* xrp = xb + (size_t)base_o * TVB + (t0 + tl) * 25 + v;
                float* op = outg + (size_t)n * CTVB + (size_t)base_o * TVB + (t0 + tl) * 25 + v;
                #pragma unroll
                for (int r = 0; r < 4; ++r) {
                    float xres = xrp[(size_t)r * TVB];            // fp32 residual, L2-hot
                    float val = fmaf(acc[r], invr[r], add0r[r]) + xres;
                    op[(size_t)r * TVB] = fmaxf(val, 0.f);
                }
            }
        }
        __syncthreads();
    }
}

extern "C" void kernel_launch(void* const* d_in, const int* in_sizes, int n_in,
                              void* d_out, int out_size, void* d_ws, size_t ws_size,
                              hipStream_t stream) {
    const float* x    = (const float*)d_in[0];
    const float* Ast  = (const float*)d_in[1];
    const float* Gat  = (const float*)d_in[2];
    const float* Wg   = (const float*)d_in[3];
    const float* bg   = (const float*)d_in[4];
    const float* Wa   = (const float*)d_in[5];
    const float* ba   = (const float*)d_in[6];
    const float* Wb   = (const float*)d_in[7];
    const float* bb   = (const float*)d_in[8];
    const float* gam  = (const float*)d_in[9];
    const float* bet  = (const float*)d_in[10];
    const float* rmu  = (const float*)d_in[11];
    const float* rva  = (const float*)d_in[12];
    float* out = (float*)d_out;
    float* Sws = (float*)d_ws;   // 192*625 floats = 480 KB

    hipMemsetAsync(Sws, 0, 192 * 625 * sizeof(float), stream);
    kA<<<dim3(25, 64), 256, 0, stream>>>(x, Wa, ba, Wb, bb, Sws);
    kS<<<dim3(192), 64, 0, stream>>>(Sws, Ast, Gat);
    kB<<<dim3(100, 64), 256, 0, stream>>>(x, Wg, bg, gam, bet, rmu, rva, Sws, out);
}

// Round 5
// 389.911 us; speedup vs baseline: 1.0538x; 1.0538x over previous
//
#include <hip/hip_runtime.h>

typedef unsigned short u16;
typedef __attribute__((ext_vector_type(8))) short short8;
typedef __attribute__((ext_vector_type(4))) float float4v;

#define TVB 7500
#define CTVB 480000

union U8S { short8 s; uint4 u; };

static __device__ __forceinline__ float bf2f(u16 a) {
    union { unsigned u; float f; } x; x.u = ((unsigned)a) << 16; return x.f;
}
static __device__ __forceinline__ u16 f2bfc(float f) {   // round-half-up, 2 ops
    union { float f; unsigned u; } x; x.f = f;
    return (u16)((x.u + 0x8000u) >> 16);
}
// pack bf16(a) | bf16(b)<<16 : 2 adds + 1 v_perm
static __device__ __forceinline__ unsigned pk2(float a, float b) {
    union { float f; unsigned u; } xa, xb; xa.f = a; xb.f = b;
    return __builtin_amdgcn_perm(xb.u + 0x8000u, xa.u + 0x8000u, 0x07060302u);
}

// ---------------- Kernel A: attention score partials S_i[n,u,v] ----------------
// grid (25, 64), block 256. 12 t's per block (3 groups of 4).
// Writes per-block partials (NO atomics) to part[((tb*64+n)*3+i)*625 + u*25+v].
__global__ __launch_bounds__(256, 3) void kA(
    const float* __restrict__ xg, const float* __restrict__ Wa, const float* __restrict__ ba,
    const float* __restrict__ Wb, const float* __restrict__ bb, float* __restrict__ part)
{
    __shared__ u16 xT[4][32][72];   // xT[tt][u][c]
    __shared__ u16 asT[3][32][72];  // a^T : [i][u][k=tt*16+ci]
    __shared__ u16 bsT[3][32][72];  // b^T : [i][v][k]
    const int tid  = threadIdx.x;
    const int lane = tid & 63;
    const int w    = tid >> 6;
    const int l15  = lane & 15;
    const int q    = lane >> 4;
    const int n    = blockIdx.y;
    const int t0   = blockIdx.x * 12;

    // zero xT pad rows u=25..31 (once; staging never touches them)
    for (int e = tid; e < 4 * 7 * 72; e += 256) {
        int tt = e / 504;
        int r  = e - tt * 504;
        xT[tt][25 + r / 72][r % 72] = 0;
    }

    // Wa/Wb A-frags (wave w<3 = subset i). A[m=ci][k=c]. 2 float4 loads + 4 perms per frag.
    short8 waf[2], wbf[2];
    float ba_r[4], bb_r[4];
    if (w < 3) {
        #pragma unroll
        for (int kf = 0; kf < 2; ++kf) {
            const float* pa = Wa + w * 1024 + l15 * 64 + kf * 32 + q * 8;
            const float* pb = Wb + w * 1024 + l15 * 64 + kf * 32 + q * 8;
            float4 a0 = *(const float4*)pa, a1 = *(const float4*)(pa + 4);
            float4 b0 = *(const float4*)pb, b1 = *(const float4*)(pb + 4);
            U8S ta, tb;
            ta.u = make_uint4(pk2(a0.x, a0.y), pk2(a0.z, a0.w), pk2(a1.x, a1.y), pk2(a1.z, a1.w));
            tb.u = make_uint4(pk2(b0.x, b0.y), pk2(b0.z, b0.w), pk2(b1.x, b1.y), pk2(b1.z, b1.w));
            waf[kf] = ta.s; wbf[kf] = tb.s;
        }
        #pragma unroll
        for (int r = 0; r < 4; ++r) {
            ba_r[r] = ba[w * 16 + q * 4 + r];
            bb_r[r] = bb[w * 16 + q * 4 + r];
        }
    }

    float4v accS[3];
    #pragma unroll
    for (int i = 0; i < 3; ++i) accS[i] = (float4v){0.f, 0.f, 0.f, 0.f};

    const float* xb = xg + (size_t)n * CTVB;

    for (int g = 0; g < 3; ++g) {
        __syncthreads();
        // stage 4 t's transposed, paired float2 loads (t0+g*4 is even -> 8B aligned)
        const float* xs = xb + (t0 + g * 4) * 25;
        #pragma unroll 2
        for (int e = tid; e < 3200; e += 256) {
            int c = e / 50;
            int p = e - c * 50;
            int j = 2 * p;
            float2 v2 = *(const float2*)(xs + c * TVB + j);
            int tt0 = j / 25, u0 = j - tt0 * 25;
            int j1 = j + 1;
            int tt1 = j1 / 25, u1 = j1 - tt1 * 25;
            xT[tt0][u0][c] = f2bfc(v2.x);
            xT[tt1][u1][c] = f2bfc(v2.y);
        }
        __syncthreads();
        if (w < 3) {
            #pragma unroll
            for (int tt = 0; tt < 4; ++tt) {
                float4v aA0 = {0,0,0,0}, aA1 = {0,0,0,0}, aB0 = {0,0,0,0}, aB1 = {0,0,0,0};
                #pragma unroll
                for (int kf = 0; kf < 2; ++kf) {
                    short8 x0 = *(const short8*)&xT[tt][l15][kf * 32 + q * 8];
                    short8 x1 = *(const short8*)&xT[tt][16 + l15][kf * 32 + q * 8];
                    aA0 = __builtin_amdgcn_mfma_f32_16x16x32_bf16(waf[kf], x0, aA0, 0, 0, 0);
                    aA1 = __builtin_amdgcn_mfma_f32_16x16x32_bf16(waf[kf], x1, aA1, 0, 0, 0);
                    aB0 = __builtin_amdgcn_mfma_f32_16x16x32_bf16(wbf[kf], x0, aB0, 0, 0, 0);
                    aB1 = __builtin_amdgcn_mfma_f32_16x16x32_bf16(wbf[kf], x1, aB1, 0, 0, 0);
                }
                int kb = tt * 16 + q * 4;
                uint2 ua0 = { pk2(aA0[0] + ba_r[0], aA0[1] + ba_r[1]), pk2(aA0[2] + ba_r[2], aA0[3] + ba_r[3]) };
                uint2 ua1 = { pk2(aA1[0] + ba_r[0], aA1[1] + ba_r[1]), pk2(aA1[2] + ba_r[2], aA1[3] + ba_r[3]) };
                uint2 ub0 = { pk2(aB0[0] + bb_r[0], aB0[1] + bb_r[1]), pk2(aB0[2] + bb_r[2], aB0[3] + bb_r[3]) };
                uint2 ub1 = { pk2(aB1[0] + bb_r[0], aB1[1] + bb_r[1]), pk2(aB1[2] + bb_r[2], aB1[3] + bb_r[3]) };
                *(uint2*)&asT[w][l15][kb]      = ua0;
                *(uint2*)&asT[w][16 + l15][kb] = ua1;
                *(uint2*)&bsT[w][l15][kb]      = ub0;
                *(uint2*)&bsT[w][16 + l15][kb] = ub1;
            }
        }
        __syncthreads();
        const int mt = w >> 1, nt = w & 1;
        #pragma unroll
        for (int i = 0; i < 3; ++i) {
            #pragma unroll
            for (int ks = 0; ks < 2; ++ks) {
                short8 af  = *(const short8*)&asT[i][mt * 16 + l15][ks * 32 + q * 8];
                short8 bf_ = *(const short8*)&bsT[i][nt * 16 + l15][ks * 32 + q * 8];
                accS[i] = __builtin_amdgcn_mfma_f32_16x16x32_bf16(af, bf_, accS[i], 0, 0, 0);
            }
        }
    }
    // plain-store partial tail (each (u,v) slot owned by exactly one lane)
    const int mt = w >> 1, nt = w & 1;
    const size_t pbase = ((size_t)blockIdx.x * 64 + n) * 3;
    #pragma unroll
    for (int i = 0; i < 3; ++i) {
        #pragma unroll
        for (int r = 0; r < 4; ++r) {
            int u = mt * 16 + q * 4 + r;
            int v = nt * 16 + l15;
            if (u < 25 && v < 25)
                part[(pbase + i) * 625 + u * 25 + v] = accS[i][r];
        }
    }
}

// ---------------- Kernel S: reduce partials + softmax over u + A_static + graph_attn ----------------
// grid 192 (= i*64+n), block 256.
__global__ __launch_bounds__(256) void kS(const float* __restrict__ part, float* __restrict__ Sws,
    const float* __restrict__ Ast, const float* __restrict__ Gat)
{
    __shared__ float ssum[625];
    const int g = blockIdx.x;       // g = i*64 + n
    const int i = g >> 6;
    const int n = g & 63;
    const int tid = threadIdx.x;
    for (int e = tid; e < 625; e += 256) {
        float s = 0.f;
        #pragma unroll 5
        for (int tb = 0; tb < 25; ++tb)
            s += part[(((size_t)tb * 64 + n) * 3 + i) * 625 + e];
        ssum[e] = s;
    }
    __syncthreads();
    if (tid < 25) {
        const int v = tid;
        float vals[25];
        float m = -1e30f;
        #pragma unroll
        for (int u = 0; u < 25; ++u) {
            float s = ssum[u * 25 + v] * (1.0f / 4800.0f);
            vals[u] = s;
            m = fmaxf(m, s);
        }
        float sum = 0.f;
        #pragma unroll
        for (int u = 0; u < 25; ++u) { float e = __expf(vals[u] - m); vals[u] = e; sum += e; }
        float isum = 1.f / sum;
        #pragma unroll
        for (int u = 0; u < 25; ++u) {
            int idx = i * 625 + u * 25 + v;
            Sws[g * 625 + u * 25 + v] = vals[u] * isum + Ast[idx] + Gat[idx];
        }
    }
}

// ---------------- Kernel B: out = relu(BN(sum_i Wg_i @ (X_t @ P_i)) + x) ----------------
// grid (100, 64), block 256. 3 t's per block. LDS 32.7KB -> 4 blocks/CU.
__global__ __launch_bounds__(256, 4) void kB(
    const float* __restrict__ xg, const float* __restrict__ Wgp, const float* __restrict__ bgp,
    const float* __restrict__ gam, const float* __restrict__ bet, const float* __restrict__ rmu,
    const float* __restrict__ rva, const float* __restrict__ attnw, float* __restrict__ outg)
{
    __shared__ u16 xsu[3][64][32];   // x[c][u], u padded to 32 with zeros
    __shared__ u16 ysT[32][200];     // Ycat^T : [v][k=i*64+c]
    __shared__ u16 pTs[3][32][40];   // attn^T : [i][v][u], zero-padded
    const int tid  = threadIdx.x;
    const int lane = tid & 63;
    const int w    = tid >> 6;
    const int l15  = lane & 15;
    const int q    = lane >> 4;
    const int n    = blockIdx.y;
    const int t0   = blockIdx.x * 3;

    for (int e = tid; e < 3 * 32 * 40; e += 256) ((u16*)pTs)[e] = 0;
    const float* xb = xg + (size_t)n * CTVB;
    // x staging: per c, run of 75 floats (3 t): 37 float2 pairs + 1 tail
    #pragma unroll 2
    for (int e = tid; e < 64 * 38; e += 256) {
        int c = e / 38;
        int p = e - c * 38;
        const float* src = xb + c * TVB + t0 * 25;
        if (p < 37) {
            int j = 2 * p;
            float2 v2 = *(const float2*)(src + j);
            int tt0 = j / 25, u0 = j - tt0 * 25;
            int j1 = j + 1;
            int tt1 = j1 / 25, u1 = j1 - tt1 * 25;
            xsu[tt0][c][u0] = f2bfc(v2.x);
            xsu[tt1][c][u1] = f2bfc(v2.y);
        } else {
            xsu[2][c][24] = f2bfc(src[74]);
        }
    }
    // zero pads u=25..31
    for (int e = tid; e < 3 * 64 * 7; e += 256) {
        int tt = e / 448;
        int r  = e - tt * 448;
        xsu[tt][r / 7][25 + r % 7] = 0;
    }
    for (int e = tid; e < 1875; e += 256) {
        int i = e / 625;
        int r = e - i * 625;
        int u = r / 25;
        int v = r - u * 25;
        pTs[i][v][u] = f2bfc(attnw[(i * 64 + n) * 625 + r]);
    }

    // Wg A-frags: 2 float4 loads + 4 perms per frag, held in registers.
    short8 wgf[6];
    #pragma unroll
    for (int kf = 0; kf < 6; ++kf) {
        int i  = kf >> 1;
        int c0 = (kf & 1) * 32 + q * 8;
        const float* p = Wgp + i * 4096 + (w * 16 + l15) * 64 + c0;
        float4 f0 = *(const float4*)p, f1 = *(const float4*)(p + 4);
        U8S t;
        t.u = make_uint4(pk2(f0.x, f0.y), pk2(f0.z, f0.w), pk2(f1.x, f1.y), pk2(f1.z, f1.w));
        wgf[kf] = t.s;
    }
    // BN constants per lane (o = w*16 + q*4 + r)
    float invr[4], add0r[4];
    #pragma unroll
    for (int r = 0; r < 4; ++r) {
        int o = w * 16 + q * 4 + r;
        float gv = gam[o], bt = bet[o], mu = rmu[o], vv = rva[o];
        float bgs = bgp[o] + bgp[64 + o] + bgp[128 + o];
        float iv = gv * rsqrtf(vv + 1e-5f);
        invr[r] = iv;
        add0r[r] = (bgs - mu) * iv + bt;
    }
    __syncthreads();
    // P B-frags in registers: B[k=u][n=v]
    short8 pf[3][2];
    #pragma unroll
    for (int i = 0; i < 3; ++i)
        #pragma unroll
        for (int nt = 0; nt < 2; ++nt)
            pf[i][nt] = *(const short8*)&pTs[i][nt * 16 + l15][q * 8];

    #pragma unroll
    for (int tl = 0; tl < 3; ++tl) {
        // Phase A: Y_i = X_t @ P_i
        short8 xf = *(const short8*)&xsu[tl][w * 16 + l15][q * 8];
        #pragma unroll
        for (int i = 0; i < 3; ++i) {
            #pragma unroll
            for (int nt = 0; nt < 2; ++nt) {
                float4v acc = {0, 0, 0, 0};
                acc = __builtin_amdgcn_mfma_f32_16x16x32_bf16(xf, pf[i][nt], acc, 0, 0, 0);
                uint2 pk = { pk2(acc[0], acc[1]), pk2(acc[2], acc[3]) };
                *(uint2*)&ysT[nt * 16 + l15][i * 64 + w * 16 + q * 4] = pk;
            }
        }
        __syncthreads();
        // Phase B: Out_t = WgCat(64x192) @ Ycat(192x25pad32); epilogue fused
        #pragma unroll
        for (int nt = 0; nt < 2; ++nt) {
            float4v acc = {0, 0, 0, 0};
            #pragma unroll
            for (int kf = 0; kf < 6; ++kf) {
                short8 yf = *(const short8*)&ysT[nt * 16 + l15][kf * 32 + q * 8];
                acc = __builtin_amdgcn_mfma_f32_16x16x32_bf16(wgf[kf], yf, acc, 0, 0, 0);
            }
            int v = nt * 16 + l15;
            if (v < 25) {
                int base_o = w * 16 + q * 4;
                float* op = outg + (size_t)n * CTVB + (size_t)base_o * TVB + (t0 + tl) * 25 + v;
                #pragma unroll
                for (int r = 0; r < 4; ++r) {
                    int o = base_o + r;
                    float xres = bf2f(xsu[tl][o][v]);   // residual from LDS bf16 (r2-proven)
                    float val = fmaf(acc[r], invr[r], add0r[r]) + xres;
                    op[(size_t)r * TVB] = fmaxf(val, 0.f);
                }
            }
        }
        __syncthreads();
    }
}

extern "C" void kernel_launch(void* const* d_in, const int* in_sizes, int n_in,
                              void* d_out, int out_size, void* d_ws, size_t ws_size,
                              hipStream_t stream) {
    const float* x    = (const float*)d_in[0];
    const float* Ast  = (const float*)d_in[1];
    const float* Gat  = (const float*)d_in[2];
    const float* Wg   = (const float*)d_in[3];
    const float* bg   = (const float*)d_in[4];
    const float* Wa   = (const float*)d_in[5];
    const float* ba   = (const float*)d_in[6];
    const float* Wb   = (const float*)d_in[7];
    const float* bb   = (const float*)d_in[8];
    const float* gam  = (const float*)d_in[9];
    const float* bet  = (const float*)d_in[10];
    const float* rmu  = (const float*)d_in[11];
    const float* rva  = (const float*)d_in[12];
    float* out  = (float*)d_out;
    float* Sws  = (float*)d_ws;    // 192*625 floats = 480 KB (final attn)
    float* part = out;             // 25*192*625 floats = 12 MB scratch in d_out;
                                   // consumed by kS before kB fully overwrites d_out.

    kA<<<dim3(25, 64), 256, 0, stream>>>(x, Wa, ba, Wb, bb, part);
    kS<<<dim3(192), 256, 0, stream>>>(part, Sws, Ast, Gat);
    kB<<<dim3(100, 64), 256, 0, stream>>>(x, Wg, bg, gam, bet, rmu, rva, Sws, out);
}